// Round 14
// baseline (284.629 us; speedup 1.0000x reference)
//
#include <hip/hip_runtime.h>

#define G 32
#define NCELL (G * G * G)       // 32768
#define C_IN 3
#define C_OUT 64
#define PBLK 64                 // chunks per vtype; histo grid = 4*PBLK = 256
#define HTHREADS 1024
#define SCAN_T 1024

typedef float          f32x4  __attribute__((ext_vector_type(4)));
typedef int            i32x4  __attribute__((ext_vector_type(4)));
typedef unsigned short u16x4  __attribute__((ext_vector_type(4)));

// ws layout:
//   sums[NCELL*3] f32 | cnt[NCELL] f32 | avg[NCELL*3] f32
//   | convout[NCELL*64] f32 | cnti[NCELL] i32 | cellbase[NCELL] i32
//   | chunkoff[PBLK*NCELL] i32 | cellid[n pad] u16 | sortedidx[n pad] i32
//   | partial[4][PBLK][NCELL] f32

// ---------------- cellid precompute: coords read ONCE, u16 out --------
__global__ void cellid_kernel(const i32x4* __restrict__ coords4,
                              unsigned short* __restrict__ cellid, int n) {
    int t = blockIdx.x * blockDim.x + threadIdx.x;   // one thread = 4 points
    int base = t * 4;
    if (base >= n) return;
    i32x4 a = coords4[t * 3 + 0];
    i32x4 b = coords4[t * 3 + 1];
    i32x4 c = coords4[t * 3 + 2];
    int c0 = (((a.x >> 4) * G + (a.y >> 4)) * G + (a.z >> 4));
    int c1 = (((a.w >> 4) * G + (b.x >> 4)) * G + (b.y >> 4));
    int c2 = (((b.z >> 4) * G + (b.w >> 4)) * G + (c.x >> 4));
    int c3 = (((c.y >> 4) * G + (c.z >> 4)) * G + (c.w >> 4));
    if (base + 3 < n) {
        u16x4 r = {(unsigned short)c0, (unsigned short)c1,
                   (unsigned short)c2, (unsigned short)c3};
        *(u16x4*)&cellid[base] = r;
    } else {
        cellid[base] = (unsigned short)c0;
        if (base + 1 < n) cellid[base + 1] = (unsigned short)c1;
        if (base + 2 < n) cellid[base + 2] = (unsigned short)c2;
    }
}

// -------- vtype-split LDS histogram; same-chunk blocks share an XCD ----
__global__ __launch_bounds__(HTHREADS) void histo_kernel(
    const unsigned short* __restrict__ cellid,
    const float* __restrict__ feats,
    float* __restrict__ partial,   // [4][PBLK][NCELL]
    int n, int ppc) {
    __shared__ __align__(16) float h[NCELL];   // 128 KB
    int xcd = blockIdx.x & 7;
    int s   = blockIdx.x >> 3;
    int chunk = xcd * 8 + (s >> 2);    // 8 chunks per XCD
    int vtype = s & 3;

    f32x4* h4 = (f32x4*)h;
    for (int t = threadIdx.x; t < NCELL / 4; t += HTHREADS)
        h4[t] = (f32x4){0.f, 0.f, 0.f, 0.f};
    __syncthreads();

    int start = chunk * ppc;
    int end = start + ppc; if (end > n) end = n;
    if (vtype < 3) {
        for (int i = start + threadIdx.x; i < end; i += HTHREADS) {
            int c = cellid[i];
            atomicAdd(&h[c], feats[i * 3 + vtype]);
        }
    } else {
        for (int i = start + threadIdx.x; i < end; i += HTHREADS) {
            int c = cellid[i];
            atomicAdd(&h[c], 1.0f);
        }
    }
    __syncthreads();

    f32x4* pp = (f32x4*)(partial + ((size_t)vtype * PBLK + chunk) * NCELL);
    for (int t = threadIdx.x; t < NCELL / 4; t += HTHREADS)
        pp[t] = h4[t];
}

// ------- reduce partials -> per-cell average + integer count ----------
__global__ void reduce_kernel(const float* __restrict__ partial,
                              float* __restrict__ avg,
                              int* __restrict__ cnti) {
    int cell = blockIdx.x * blockDim.x + threadIdx.x;
    if (cell >= NCELL) return;
    float s0 = 0.f, s1 = 0.f, s2 = 0.f, c = 0.f;
    for (int p = 0; p < PBLK; ++p) {
        s0 += partial[((size_t)0 * PBLK + p) * NCELL + cell];
        s1 += partial[((size_t)1 * PBLK + p) * NCELL + cell];
        s2 += partial[((size_t)2 * PBLK + p) * NCELL + cell];
        c  += partial[((size_t)3 * PBLK + p) * NCELL + cell];
    }
    float inv = c > 0.f ? 1.0f / c : 0.f;
    avg[cell * 3 + 0] = s0 * inv;
    avg[cell * 3 + 1] = s1 * inv;
    avg[cell * 3 + 2] = s2 * inv;
    cnti[cell] = (int)(c + 0.5f);
}

// ------- exclusive scan over 32768 cell counts (single block) ---------
__global__ __launch_bounds__(SCAN_T) void scan_kernel(
    const int* __restrict__ cnti, int* __restrict__ cellbase) {
    __shared__ int ls[SCAN_T];
    int t = threadIdx.x;
    const int K = NCELL / SCAN_T;   // 32 cells per thread
    int c0 = t * K;
    int s = 0;
#pragma unroll
    for (int k = 0; k < K; ++k) s += cnti[c0 + k];
    int val = s;
    ls[t] = val;
    __syncthreads();
    for (int off = 1; off < SCAN_T; off <<= 1) {
        int other = (t >= off) ? ls[t - off] : 0;
        __syncthreads();
        val += other;
        ls[t] = val;
        __syncthreads();
    }
    int run = val - s;              // exclusive prefix of this thread's range
    for (int k = 0; k < K; ++k) {
        cellbase[c0 + k] = run;
        run += cnti[c0 + k];
    }
}

// ------- per-chunk per-cell base offsets from existing partials -------
__global__ void chunkoff_kernel(const float* __restrict__ partial,
                                const int* __restrict__ cellbase,
                                int* __restrict__ chunkoff) {
    int c = blockIdx.x * blockDim.x + threadIdx.x;
    if (c >= NCELL) return;
    int off = cellbase[c];
    for (int p = 0; p < PBLK; ++p) {
        chunkoff[(size_t)p * NCELL + c] = off;
        off += (int)(partial[((size_t)3 * PBLK + p) * NCELL + c] + 0.5f);
    }
}

// ------- counting-sort scatter: point indices grouped by cell ---------
__global__ __launch_bounds__(HTHREADS) void scatter_idx_kernel(
    const unsigned short* __restrict__ cellid,
    const int* __restrict__ chunkoff,
    int* __restrict__ sortedidx, int n, int ppc) {
    __shared__ int ctr[NCELL];   // 128 KB of per-cell cursors
    int p = blockIdx.x;
    for (int t = threadIdx.x; t < NCELL; t += HTHREADS)
        ctr[t] = chunkoff[(size_t)p * NCELL + t];
    __syncthreads();
    int start = p * ppc;
    int end = start + ppc; if (end > n) end = n;
    for (int i = start + threadIdx.x; i < end; i += HTHREADS) {
        int c = cellid[i];
        int pos = atomicAdd(&ctr[c], 1);
        sortedidx[pos] = i;
    }
}

// ---------------- dense 3^3 conv -> f32 table (8 MB) ------------------
__global__ void conv_kernel(const float* __restrict__ avg,
                            const float* __restrict__ W,   // [64][3][27]
                            float* __restrict__ convout) {
    __shared__ float wlds[C_OUT * C_IN * 27];
    for (int t = threadIdx.x; t < C_OUT * C_IN * 27; t += blockDim.x)
        wlds[t] = W[t];
    __syncthreads();

    int cell = blockIdx.x * blockDim.x + threadIdx.x;
    if (cell >= NCELL) return;
    int z = cell & 31;
    int y = (cell >> 5) & 31;
    int x = cell >> 10;

    float acc[C_OUT];
#pragma unroll
    for (int c = 0; c < C_OUT; ++c) acc[c] = 0.f;

    for (int kd = 0; kd < 3; ++kd) {
        int nx = x + kd - 1;
        if (nx < 0 || nx >= G) continue;
        for (int kh = 0; kh < 3; ++kh) {
            int ny = y + kh - 1;
            if (ny < 0 || ny >= G) continue;
            for (int kw = 0; kw < 3; ++kw) {
                int nz = z + kw - 1;
                if (nz < 0 || nz >= G) continue;
                int nc = (nx * G + ny) * G + nz;
                float g0 = avg[nc * 3 + 0];   // empty cells are exactly 0
                float g1 = avg[nc * 3 + 1];
                float g2 = avg[nc * 3 + 2];
                int koff = (kd * 3 + kh) * 3 + kw;
#pragma unroll
                for (int co = 0; co < C_OUT; ++co) {
                    const float* wp = &wlds[co * C_IN * 27 + koff];
                    acc[co] += wp[0] * g0 + wp[27] * g1 + wp[54] * g2;
                }
            }
        }
    }
    float* op = &convout[(size_t)cell * C_OUT];
#pragma unroll
    for (int co = 0; co < C_OUT; ++co) op[co] = acc[co];
}

// ------- cell-major broadcast: pure 256-B coalesced write stream ------
// One wave per cell: lane l holds channel l's f32 in a register; loop over
// the cell's point list writing 64x4B = 256 B contiguous per point.
__global__ __launch_bounds__(256) void broadcast_kernel(
    const float* __restrict__ convout,
    const int* __restrict__ cellbase,
    const int* __restrict__ cnti,
    const int* __restrict__ sortedidx,
    float* __restrict__ out) {
    int cell = blockIdx.x * 4 + (threadIdx.x >> 6);
    int lane = threadIdx.x & 63;
    float v = convout[(size_t)cell * C_OUT + lane];
    int s = cellbase[cell];
    int e = s + cnti[cell];
    for (int j = s; j < e; ++j) {
        int idx = sortedidx[j];            // wave-uniform scalar load
        out[(size_t)idx * C_OUT + lane] = v;
    }
}

// ---------------- fallback path (tiny ws), all f32 ----------------
__global__ void scatter_atomic_kernel(const int* __restrict__ coords,
                                      const float* __restrict__ feats,
                                      float* __restrict__ sums,
                                      float* __restrict__ cnt, int n) {
    int i = blockIdx.x * blockDim.x + threadIdx.x;
    if (i >= n) return;
    int x = coords[i * 3 + 0] >> 4;
    int y = coords[i * 3 + 1] >> 4;
    int z = coords[i * 3 + 2] >> 4;
    int cell = (x * G + y) * G + z;
    atomicAdd(&sums[cell * 3 + 0], feats[i * 3 + 0]);
    atomicAdd(&sums[cell * 3 + 1], feats[i * 3 + 1]);
    atomicAdd(&sums[cell * 3 + 2], feats[i * 3 + 2]);
    atomicAdd(&cnt[cell], 1.0f);
}

__global__ void avg_kernel(const float* __restrict__ sums,
                           const float* __restrict__ cnt,
                           float* __restrict__ avg) {
    int cell = blockIdx.x * blockDim.x + threadIdx.x;
    if (cell >= NCELL) return;
    float c = cnt[cell];
    float inv = c > 0.f ? 1.0f / c : 0.f;
    avg[cell * 3 + 0] = sums[cell * 3 + 0] * inv;
    avg[cell * 3 + 1] = sums[cell * 3 + 1] * inv;
    avg[cell * 3 + 2] = sums[cell * 3 + 2] * inv;
}

__global__ void gather_coords_kernel(const int* __restrict__ coords,
                                     const f32x4* __restrict__ convout,
                                     f32x4* __restrict__ out, int n) {
    long g = (long)blockIdx.x * blockDim.x + threadIdx.x;
    int i = (int)(g >> 4);
    int c4 = (int)(g & 15);
    if (i >= n) return;
    int x = coords[i * 3 + 0] >> 4;
    int y = coords[i * 3 + 1] >> 4;
    int z = coords[i * 3 + 2] >> 4;
    int cell = (x * G + y) * G + z;
    out[(size_t)i * 16 + c4] = convout[(size_t)cell * 16 + c4];
}

extern "C" void kernel_launch(void* const* d_in, const int* in_sizes, int n_in,
                              void* d_out, int out_size, void* d_ws, size_t ws_size,
                              hipStream_t stream) {
    const int*   coords = (const int*)d_in[0];
    const float* feats  = (const float*)d_in[1];
    const float* W      = (const float*)d_in[2];
    float* out = (float*)d_out;
    int n = in_sizes[0] / 3;   // 2,000,000

    float*          sums      = (float*)d_ws;
    float*          cnt       = sums + NCELL * 3;
    float*          avg       = cnt + NCELL;
    float*          convout   = avg + NCELL * 3;
    int*            cnti      = (int*)(convout + (size_t)NCELL * 64);
    int*            cellbase  = cnti + NCELL;
    int*            chunkoff  = cellbase + NCELL;
    unsigned short* cellid    = (unsigned short*)(chunkoff + (size_t)PBLK * NCELL);
    size_t          cid_elems = ((size_t)n + 7) & ~(size_t)7;   // 16B align
    int*            sortedidx = (int*)(cellid + cid_elems);
    float*          partial   = (float*)(sortedidx + cid_elems);

    size_t need = (size_t)NCELL * (3 + 1 + 3 + 64 + 1 + 1 + PBLK) * 4 +
                  cid_elems * 2 + cid_elems * 4 +
                  (size_t)4 * PBLK * NCELL * 4;
    bool fast = (ws_size >= need);

    if (fast) {
        int npt4 = (n + 3) / 4;
        cellid_kernel<<<(npt4 + 255) / 256, 256, 0, stream>>>(
            (const i32x4*)coords, cellid, n);
        int ppc = (n + PBLK - 1) / PBLK;
        histo_kernel<<<4 * PBLK, HTHREADS, 0, stream>>>(cellid, feats, partial, n, ppc);
        reduce_kernel<<<NCELL / 256, 256, 0, stream>>>(partial, avg, cnti);
        scan_kernel<<<1, SCAN_T, 0, stream>>>(cnti, cellbase);
        chunkoff_kernel<<<NCELL / 256, 256, 0, stream>>>(partial, cellbase, chunkoff);
        scatter_idx_kernel<<<PBLK, HTHREADS, 0, stream>>>(cellid, chunkoff,
                                                          sortedidx, n, ppc);
        conv_kernel<<<NCELL / 256, 256, 0, stream>>>(avg, W, convout);
        broadcast_kernel<<<NCELL / 4, 256, 0, stream>>>(convout, cellbase, cnti,
                                                        sortedidx, out);
    } else {
        hipMemsetAsync(d_ws, 0, NCELL * 4 * sizeof(float), stream);
        scatter_atomic_kernel<<<(n + 255) / 256, 256, 0, stream>>>(coords, feats, sums, cnt, n);
        avg_kernel<<<NCELL / 256, 256, 0, stream>>>(sums, cnt, avg);
        conv_kernel<<<NCELL / 256, 256, 0, stream>>>(avg, W, convout);
        long total = (long)n * 16;
        gather_coords_kernel<<<(int)((total + 255) / 256), 256, 0, stream>>>(
            coords, (const f32x4*)convout, (f32x4*)out, n);
    }
}